// Round 3
// baseline (2883.686 us; speedup 1.0000x reference)
//
#include <hip/hip_runtime.h>
#include <stdint.h>

// ---------------- common ----------------
typedef __bf16 bf16x8 __attribute__((ext_vector_type(8)));
typedef float f32x4 __attribute__((ext_vector_type(4)));
typedef unsigned short u16;
typedef unsigned int u32;

__device__ __forceinline__ u16 f2bf(float f) {
  u32 u = __float_as_uint(f);
  return (u16)((u + 0x7fffu + ((u >> 16) & 1u)) >> 16);
}

__device__ __forceinline__ void gload16(const void* g, void* l) {
  __builtin_amdgcn_global_load_lds((const __attribute__((address_space(1))) u32*)g,
                                   (__attribute__((address_space(3))) u32*)l, 16, 0, 0);
}

__device__ __forceinline__ f32x4 mfma16(bf16x8 a, bf16x8 b, f32x4 c) {
  return __builtin_amdgcn_mfma_f32_16x16x32_bf16(a, b, c, 0, 0, 0);
}

// ---------------- fp32 -> bf16 convert (weights) ----------------
__global__ void cvt_k(const float* __restrict__ in, u16* __restrict__ out, int n4) {
  int i = blockIdx.x * blockDim.x + threadIdx.x;
  int stride = gridDim.x * blockDim.x;
  for (; i < n4; i += stride) {
    float4 v = ((const float4*)in)[i];
    ushort4 o;
    o.x = f2bf(v.x); o.y = f2bf(v.y); o.z = f2bf(v.z); o.w = f2bf(v.w);
    ((ushort4*)out)[i] = o;
  }
}

// ---------------- LayerNorm (row=512). MODE 0: a+pos[row%S]; MODE 1: a+bs[row] ----------------
template<int MODE>
__global__ __launch_bounds__(128) void ln_k(const float* __restrict__ a, const float* __restrict__ bs,
                                            const float* __restrict__ g, const float* __restrict__ be,
                                            float* __restrict__ ox, u16* __restrict__ oxb, int S) {
  int row = blockIdx.x;
  int t = threadIdx.x;
  const float4* ar = (const float4*)(a + (size_t)row * 512);
  size_t brow = (MODE == 0) ? (size_t)(row % S) : (size_t)row;
  const float4* br = (const float4*)(bs + brow * 512);
  float4 va = ar[t], vb = br[t];
  float4 v;
  v.x = va.x + vb.x; v.y = va.y + vb.y; v.z = va.z + vb.z; v.w = va.w + vb.w;
  float s = v.x + v.y + v.z + v.w;
  float sq = v.x * v.x + v.y * v.y + v.z * v.z + v.w * v.w;
#pragma unroll
  for (int m = 1; m < 64; m <<= 1) { s += __shfl_xor(s, m); sq += __shfl_xor(sq, m); }
  __shared__ float red[2][2];
  int wv = t >> 6;
  if ((t & 63) == 0) { red[wv][0] = s; red[wv][1] = sq; }
  __syncthreads();
  s = red[0][0] + red[1][0];
  sq = red[0][1] + red[1][1];
  float mean = s * (1.f / 512.f);
  float var = sq * (1.f / 512.f) - mean * mean;
  float rstd = rsqrtf(var + 1e-5f);
  float4 vg = ((const float4*)g)[t], vbe = ((const float4*)be)[t];
  float4 y;
  y.x = (v.x - mean) * rstd * vg.x + vbe.x;
  y.y = (v.y - mean) * rstd * vg.y + vbe.y;
  y.z = (v.z - mean) * rstd * vg.z + vbe.z;
  y.w = (v.w - mean) * rstd * vg.w + vbe.w;
  ((float4*)(ox + (size_t)row * 512))[t] = y;
  ushort4 yb;
  yb.x = f2bf(y.x); yb.y = f2bf(y.y); yb.z = f2bf(y.z); yb.w = f2bf(y.w);
  ((ushort4*)(oxb + (size_t)row * 512))[t] = yb;
}

// ---------------- row normalize to unit length, write bf16 ----------------
__global__ __launch_bounds__(128) void norm_k(const float* __restrict__ x, u16* __restrict__ o) {
  int row = blockIdx.x;
  int t = threadIdx.x;
  float4 v = ((const float4*)(x + (size_t)row * 512))[t];
  float sq = v.x * v.x + v.y * v.y + v.z * v.z + v.w * v.w;
#pragma unroll
  for (int m = 1; m < 64; m <<= 1) sq += __shfl_xor(sq, m);
  __shared__ float red[2];
  int wv = t >> 6;
  if ((t & 63) == 0) red[wv] = sq;
  __syncthreads();
  sq = red[0] + red[1];
  float rn = 1.f / (sqrtf(sq) + 1e-13f);
  ushort4 yb;
  yb.x = f2bf(v.x * rn); yb.y = f2bf(v.y * rn); yb.z = f2bf(v.z * rn); yb.w = f2bf(v.w * rn);
  ((ushort4*)(o + (size_t)row * 512))[t] = yb;
}

// ---------------- GEMM: C[M,N] = A[M,K] * Bw[N,K]^T + bias. m97-structure, 128x128 tile, BK=64 ----
// OM: 0 -> f32 out, 1 -> bf16 out, 2 -> bf16 relu out
template<int OM>
__global__ __launch_bounds__(256) void gemm_bt(const u16* __restrict__ A, const u16* __restrict__ Bw,
                                               const float* __restrict__ bias, void* __restrict__ Cp,
                                               int M, int N, int Kd) {
  __shared__ __align__(16) u16 As[128 * 64];
  __shared__ __align__(16) u16 Bs[128 * 64];
  const int tid = threadIdx.x;
  const int w = tid >> 6, lane = tid & 63, lr = lane & 15, lg = lane >> 4;
  const int m0 = blockIdx.y * 128, n0 = blockIdx.x * 128;
  const int wr = w >> 1, wc = w & 1;
  f32x4 acc[4][4] = {};
  for (int k0 = 0; k0 < Kd; k0 += 64) {
    __syncthreads();  // previous tile fully consumed
#pragma unroll
    for (int i = 0; i < 4; ++i) {
      int c = tid + 256 * i;
      int r = c >> 3, p = c & 7;
      int lc = p ^ (r & 7);  // pre-swizzled source so linear LDS dest == swizzled layout
      gload16(A + (size_t)(m0 + r) * Kd + k0 + lc * 8, &As[c * 8]);
    }
#pragma unroll
    for (int i = 0; i < 4; ++i) {
      int c = tid + 256 * i;
      int r = c >> 3, p = c & 7;
      int lc = p ^ (r & 7);
      gload16(Bw + (size_t)(n0 + r) * Kd + k0 + lc * 8, &Bs[c * 8]);
    }
    __syncthreads();  // compiler drains vmcnt before barrier
#pragma unroll
    for (int ks = 0; ks < 2; ++ks) {
      bf16x8 af[4], bfr[4];
#pragma unroll
      for (int mi = 0; mi < 4; ++mi) {
        int m = wr * 64 + mi * 16 + lr;
        int ph = (ks * 4 + lg) ^ (m & 7);
        af[mi] = *(const bf16x8*)&As[m * 64 + ph * 8];
      }
#pragma unroll
      for (int ni = 0; ni < 4; ++ni) {
        int n = wc * 64 + ni * 16 + lr;
        int ph = (ks * 4 + lg) ^ (n & 7);
        bfr[ni] = *(const bf16x8*)&Bs[n * 64 + ph * 8];
      }
#pragma unroll
      for (int mi = 0; mi < 4; ++mi)
#pragma unroll
        for (int ni = 0; ni < 4; ++ni)
          acc[mi][ni] = mfma16(af[mi], bfr[ni], acc[mi][ni]);
    }
  }
#pragma unroll
  for (int ni = 0; ni < 4; ++ni) {
    int gn = n0 + wc * 64 + ni * 16 + lr;
    float bv = bias[gn];
#pragma unroll
    for (int mi = 0; mi < 4; ++mi) {
      int gmb = m0 + wr * 64 + mi * 16 + lg * 4;
#pragma unroll
      for (int r = 0; r < 4; ++r) {
        float v = acc[mi][ni][r] + bv;
        size_t off = (size_t)(gmb + r) * N + gn;
        if (OM == 0) {
          ((float*)Cp)[off] = v;
        } else {
          if (OM == 2) v = fmaxf(v, 0.f);
          ((u16*)Cp)[off] = f2bf(v);
        }
      }
    }
  }
}

// ---------------- fused flash attention: block = (b, h, 128 q rows) ----------------
__global__ __launch_bounds__(256) void attn_k(const u16* __restrict__ qkv, const float* __restrict__ mask,
                                              u16* __restrict__ ctx, int S, int nQ) {
  __shared__ __align__(16) u16 Kl[128 * 64];
  __shared__ __align__(16) u16 Vt[64 * 136];
  __shared__ __align__(16) u16 Pl[4][16 * 72];
  __shared__ float mb[128];
  const int tid = threadIdx.x, w = tid >> 6, lane = tid & 63, lr = lane & 15, lg = lane >> 4;
  const int bid = blockIdx.x;
  const int b = bid / (8 * nQ);
  const int rem = bid % (8 * nQ);
  const int h = rem / nQ, qb = rem % nQ;
  const int q0 = qb * 128;
  const size_t bbase = (size_t)b * S * 1536;

  bf16x8 aq[2][2];
  bool tv[2];
#pragma unroll
  for (int ti = 0; ti < 2; ++ti) {
    int row = q0 + w * 32 + ti * 16;
    tv[ti] = (row < S);
    if (tv[ti]) {
#pragma unroll
      for (int ks = 0; ks < 2; ++ks)
        aq[ti][ks] = *(const bf16x8*)(qkv + bbase + (size_t)(row + lr) * 1536 + h * 64 + ks * 32 + lg * 8);
    }
  }
  f32x4 o[2][4] = {};
  float mst[2][4], lst[2][4];
#pragma unroll
  for (int ti = 0; ti < 2; ++ti)
#pragma unroll
    for (int r = 0; r < 4; ++r) { mst[ti][r] = -1e30f; lst[ti][r] = 0.f; }

  const int nsc = (S + 127) / 128;
  for (int sc = 0; sc < nsc; ++sc) {
    int base = sc * 128;
    int vs = S - base; if (vs > 128) vs = 128;
    __syncthreads();
    // stage K (swizzled), zero-fill invalid rows
#pragma unroll
    for (int i = 0; i < 4; ++i) {
      int c = tid + 256 * i;
      int rr = c >> 3, p = c & 7;
      int lc = p ^ (rr & 7);
      bf16x8 val = {};
      if (rr < vs) val = *(const bf16x8*)(qkv + bbase + (size_t)(base + rr) * 1536 + 512 + h * 64 + lc * 8);
      *(bf16x8*)&Kl[rr * 64 + p * 8] = val;
    }
    // stage V transposed [64][128] (row stride 136 for alignment/banks)
#pragma unroll
    for (int i = 0; i < 4; ++i) {
      int c = tid + 256 * i;
      int rr = c >> 3, p = c & 7;
      bf16x8 val = {};
      if (rr < vs) val = *(const bf16x8*)(qkv + bbase + (size_t)(base + rr) * 1536 + 1024 + h * 64 + p * 8);
#pragma unroll
      for (int j = 0; j < 8; ++j) Vt[(p * 8 + j) * 136 + rr] = ((const u16*)&val)[j];
    }
    if (tid < 128)
      mb[tid] = (tid < vs && mask[(size_t)b * S + base + tid] > 0.f) ? 0.f : -1e9f;
    __syncthreads();

    int nsub = (vs + 63) / 64;
#pragma unroll
    for (int ti = 0; ti < 2; ++ti) {
      if (!tv[ti]) continue;
      for (int sub = 0; sub < nsub; ++sub) {
        f32x4 sf[4] = {};
#pragma unroll
        for (int ks = 0; ks < 2; ++ks) {
#pragma unroll
          for (int ci = 0; ci < 4; ++ci) {
            int rr = sub * 64 + ci * 16 + lr;
            int ph = (ks * 4 + lg) ^ (rr & 7);
            bf16x8 kb = *(const bf16x8*)&Kl[rr * 64 + ph * 8];
            sf[ci] = mfma16(aq[ti][ks], kb, sf[ci]);
          }
        }
        float pv[4][4];
        float cm[4] = {-1e30f, -1e30f, -1e30f, -1e30f};
#pragma unroll
        for (int ci = 0; ci < 4; ++ci) {
          float bia = mb[sub * 64 + ci * 16 + lr];
#pragma unroll
          for (int r = 0; r < 4; ++r) {
            float v = sf[ci][r] * 0.125f + bia;
            pv[ci][r] = v;
            cm[r] = fmaxf(cm[r], v);
          }
        }
#pragma unroll
        for (int r = 0; r < 4; ++r) {
          float v = cm[r];
          v = fmaxf(v, __shfl_xor(v, 1));
          v = fmaxf(v, __shfl_xor(v, 2));
          v = fmaxf(v, __shfl_xor(v, 4));
          v = fmaxf(v, __shfl_xor(v, 8));
          cm[r] = v;
        }
        float al[4];
#pragma unroll
        for (int r = 0; r < 4; ++r) {
          float mn = fmaxf(mst[ti][r], cm[r]);
          al[r] = __expf(mst[ti][r] - mn);
          mst[ti][r] = mn;
        }
        float rs[4] = {0.f, 0.f, 0.f, 0.f};
#pragma unroll
        for (int ci = 0; ci < 4; ++ci)
#pragma unroll
          for (int r = 0; r < 4; ++r) {
            float p = __expf(pv[ci][r] - mst[ti][r]);
            pv[ci][r] = p;
            rs[r] += p;
          }
#pragma unroll
        for (int r = 0; r < 4; ++r) {
          float v = rs[r];
          v += __shfl_xor(v, 1); v += __shfl_xor(v, 2);
          v += __shfl_xor(v, 4); v += __shfl_xor(v, 8);
          lst[ti][r] = lst[ti][r] * al[r] + v;
        }
#pragma unroll
        for (int di = 0; di < 4; ++di)
#pragma unroll
          for (int r = 0; r < 4; ++r) o[ti][di][r] *= al[r];
        // P -> LDS (wave-private), then PV
#pragma unroll
        for (int ci = 0; ci < 4; ++ci)
#pragma unroll
          for (int r = 0; r < 4; ++r)
            Pl[w][(lg * 4 + r) * 72 + ci * 16 + lr] = f2bf(pv[ci][r]);
#pragma unroll
        for (int ks = 0; ks < 2; ++ks) {
          bf16x8 pa = *(const bf16x8*)&Pl[w][lr * 72 + ks * 32 + lg * 8];
#pragma unroll
          for (int di = 0; di < 4; ++di) {
            bf16x8 vb = *(const bf16x8*)&Vt[(di * 16 + lr) * 136 + sub * 64 + ks * 32 + lg * 8];
            o[ti][di] = mfma16(pa, vb, o[ti][di]);
          }
        }
      }
    }
  }
  // finalize
#pragma unroll
  for (int ti = 0; ti < 2; ++ti) {
    if (!tv[ti]) continue;
    int rowb = q0 + w * 32 + ti * 16 + lg * 4;
#pragma unroll
    for (int r = 0; r < 4; ++r) {
      float inv = 1.f / lst[ti][r];
#pragma unroll
      for (int di = 0; di < 4; ++di)
        ctx[(size_t)(b * S + rowb + r) * 512 + h * 64 + di * 16 + lr] = f2bf(o[ti][di][r] * inv);
    }
  }
}

// ---------------- batched cosine GEMM: cos[b, 32, 512] = qn[b] * dn[b]^T ----------------
__global__ __launch_bounds__(256) void cos_k(const u16* __restrict__ qn, const u16* __restrict__ dn,
                                             float* __restrict__ cosb) {
  int b = blockIdx.y;
  int n0 = blockIdx.x * 128;
  int tid = threadIdx.x, w = tid >> 6, lane = tid & 63, lr = lane & 15, lg = lane >> 4;
  const u16* qb_ = qn + (size_t)b * 32 * 512;
  const u16* db_ = dn + (size_t)b * 512 * 512;
  f32x4 acc[2][2] = {};
  for (int k0 = 0; k0 < 512; k0 += 32) {
    bf16x8 af[2], bfr[2];
#pragma unroll
    for (int mi = 0; mi < 2; ++mi)
      af[mi] = *(const bf16x8*)(qb_ + (size_t)(mi * 16 + lr) * 512 + k0 + lg * 8);
#pragma unroll
    for (int ni = 0; ni < 2; ++ni)
      bfr[ni] = *(const bf16x8*)(db_ + (size_t)(n0 + w * 32 + ni * 16 + lr) * 512 + k0 + lg * 8);
#pragma unroll
    for (int mi = 0; mi < 2; ++mi)
#pragma unroll
      for (int ni = 0; ni < 2; ++ni) acc[mi][ni] = mfma16(af[mi], bfr[ni], acc[mi][ni]);
  }
#pragma unroll
  for (int mi = 0; mi < 2; ++mi)
#pragma unroll
    for (int ni = 0; ni < 2; ++ni)
#pragma unroll
      for (int r = 0; r < 4; ++r)
        cosb[((size_t)b * 32 + mi * 16 + lg * 4 + r) * 512 + n0 + w * 32 + ni * 16 + lr] = acc[mi][ni][r];
}

// ---------------- kernel pooling + position bias + final dense ----------------
__global__ __launch_bounds__(256) void pool_k(const float* __restrict__ cosb, const float* __restrict__ qm,
                                              const float* __restrict__ dm, const float* __restrict__ pb,
                                              const float* __restrict__ pba, const float* __restrict__ dw,
                                              float* __restrict__ out) {
  const float MUa[11] = {1.0f, 0.9f, 0.7f, 0.5f, 0.3f, 0.1f, -0.1f, -0.3f, -0.5f, -0.7f, -0.9f};
  const float INVa[11] = {500000.f, 50.f, 50.f, 50.f, 50.f, 50.f, 50.f, 50.f, 50.f, 50.f, 50.f};
  int b = blockIdx.x, tid = threadIdx.x, lane = tid & 63, wv = tid >> 6;
  __shared__ float wd[512];
  __shared__ float red[4][11];
  __shared__ float sred[4];
  // doc_len
  float s = dm[(size_t)b * 512 + tid] + dm[(size_t)b * 512 + 256 + tid];
#pragma unroll
  for (int m = 1; m < 64; m <<= 1) s += __shfl_xor(s, m);
  if (lane == 0) sred[wv] = s;
  __syncthreads();
  float L = sred[0] + sred[1] + sred[2] + sred[3];
  int step = (int)rintf(L * 0.1f);
  for (int d = tid; d < 512; d += 256) {
    float mv = dm[(size_t)b * 512 + d];
    int cs = 1;
    if (step > 0) { cs = d / step + 1; if (cs > 10) cs = 10; }
    int pidx = (mv > 0.f) ? cs : 0;
    int aidx = (mv > 0.f) ? (1 + (d >> 6)) : 0;
    wd[d] = ((mv > 0.f) ? 1.f : 0.f) * pb[pidx] * pba[aidx];
  }
  float pk = 0.f;  // valid in tid < 11
  __syncthreads();
  for (int q = 0; q < 32; ++q) {
    float a[11] = {0.f, 0.f, 0.f, 0.f, 0.f, 0.f, 0.f, 0.f, 0.f, 0.f, 0.f};
    for (int d = tid; d < 512; d += 256) {
      float wdv = wd[d];
      if (wdv != 0.f) {
        float c = cosb[((size_t)b * 32 + q) * 512 + d];
#pragma unroll
        for (int k = 0; k < 11; ++k) {
          float t = c - MUa[k];
          a[k] += __expf(-t * t * INVa[k]) * wdv;
        }
      }
    }
#pragma unroll
    for (int k = 0; k < 11; ++k) {
      float v = a[k];
#pragma unroll
      for (int m = 1; m < 64; m <<= 1) v += __shfl_xor(v, m);
      a[k] = v;
    }
    if (lane == 0) {
#pragma unroll
      for (int k = 0; k < 11; ++k) red[wv][k] = a[k];
    }
    __syncthreads();
    if (tid < 11) {
      float sv = red[0][tid] + red[1][tid] + red[2][tid] + red[3][tid];
      pk += qm[(size_t)b * 32 + q] * logf(fmaxf(sv, 1e-10f));
    }
    __syncthreads();
  }
  if (tid < 11) red[0][tid] = pk * dw[tid];
  __syncthreads();
  if (tid == 0) {
    float t = 0.f;
#pragma unroll
    for (int k = 0; k < 11; ++k) t += red[0][k];
    out[b] = t;
  }
}

// ---------------- launch ----------------
extern "C" void kernel_launch(void* const* d_in, const int* in_sizes, int n_in,
                              void* d_out, int out_size, void* d_ws, size_t ws_size,
                              hipStream_t stream) {
  (void)in_sizes; (void)n_in; (void)out_size;
  const float* qe  = (const float*)d_in[0];
  const float* de  = (const float*)d_in[1];
  const float* qm  = (const float*)d_in[2];
  const float* dmk = (const float*)d_in[3];
  const float* pos = (const float*)d_in[4];
  const float* lng = (const float*)d_in[5];
  const float* lnb = (const float*)d_in[6];
  const float* iw  = (const float*)d_in[7];
  const float* ib  = (const float*)d_in[8];
  const float* ow  = (const float*)d_in[9];
  const float* ob  = (const float*)d_in[10];
  const float* f1w = (const float*)d_in[11];
  const float* f1b = (const float*)d_in[12];
  const float* f2w = (const float*)d_in[13];
  const float* f2b = (const float*)d_in[14];
  const float* n1g = (const float*)d_in[15];
  const float* n1b = (const float*)d_in[16];
  const float* n2g = (const float*)d_in[17];
  const float* n2b = (const float*)d_in[18];
  const float* dw  = (const float*)d_in[19];
  const float* pb  = (const float*)d_in[20];
  const float* pba = (const float*)d_in[21];
  float* out = (float*)d_out;

  uint8_t* ws = (uint8_t*)d_ws;
  size_t off = 0;
  auto alloc = [&](size_t bytes) -> void* {
    void* p = ws + off;
    off += (bytes + 255) & ~(size_t)255;
    return p;
  };
  auto a256 = [](size_t b) -> size_t { return (b + 255) & ~(size_t)255; };

  // ---- persistent buffers ----
  u16* wb_iw = (u16*)alloc((size_t)2 * 1536 * 512 * 2);
  u16* wb_ow = (u16*)alloc((size_t)2 * 512 * 512 * 2);
  u16* wb_f1 = (u16*)alloc((size_t)2 * 2048 * 512 * 2);
  u16* wb_f2 = (u16*)alloc((size_t)2 * 512 * 2048 * 2);
  u16* qn_b  = (u16*)alloc((size_t)4096 * 512 * 2);     // normalized query, bf16
  u16* dn_b  = (u16*)alloc((size_t)65536 * 512 * 2);    // normalized doc, bf16
  float* cosb = (float*)alloc((size_t)128 * 32 * 512 * 4);

  // ---- adaptive chunk size: cb docs per chunk (rows = cb*512) ----
  // chunk scratch = rows*(x:2048 + xb:1024 + big:4096 + tmp:2048) bytes = rows*9216
  int cb = 128;
  while (cb > 8) {
    size_t rows = (size_t)cb * 512;
    size_t chunk = a256(rows * 512 * 4) + a256(rows * 512 * 2) +
                   a256(rows * 2048 * 2) + a256(rows * 512 * 4);
    if (off + chunk <= ws_size) break;
    cb >>= 1;
  }
  size_t rows_max = (size_t)cb * 512;  // >= 4096 (query chunk) since cb >= 8
  float* x   = (float*)alloc(rows_max * 512 * 4);
  u16* xb    = (u16*)alloc(rows_max * 512 * 2);
  u16* big   = (u16*)alloc(rows_max * 2048 * 2);  // qkv [rows,1536] + ctx [rows,512] tail; later ff-hidden [rows,2048]
  float* tmp = (float*)alloc(rows_max * 512 * 4);

  // weights -> bf16 (same work every call; graph-safe)
  cvt_k<<<1024, 256, 0, stream>>>(iw,  wb_iw, 2 * 1536 * 512 / 4);
  cvt_k<<<1024, 256, 0, stream>>>(ow,  wb_ow, 2 * 512 * 512 / 4);
  cvt_k<<<1024, 256, 0, stream>>>(f1w, wb_f1, 2 * 2048 * 512 / 4);
  cvt_k<<<1024, 256, 0, stream>>>(f2w, wb_f2, 2 * 512 * 2048 / 4);

  // one encoder pass over `nb` batch rows of length S (M = nb*S rows resident in chunk scratch)
  auto enc = [&](const float* emb, const float* mask, int S, int nb) {
    int M = nb * S;
    u16* ctxb = big + (size_t)M * 1536;  // packed after qkv
    ln_k<0><<<M, 128, 0, stream>>>(emb, pos, lng, lnb, x, xb, S);
    int nQ = (S + 127) / 128;
    for (int l = 0; l < 2; ++l) {
      gemm_bt<1><<<dim3(12, M / 128), 256, 0, stream>>>(xb, wb_iw + (size_t)l * 1536 * 512,
                                                        ib + (size_t)l * 1536, big, M, 1536, 512);
      attn_k<<<nb * 8 * nQ, 256, 0, stream>>>(big, mask, ctxb, S, nQ);
      gemm_bt<0><<<dim3(4, M / 128), 256, 0, stream>>>(ctxb, wb_ow + (size_t)l * 512 * 512,
                                                       ob + (size_t)l * 512, tmp, M, 512, 512);
      ln_k<1><<<M, 128, 0, stream>>>(x, tmp, n1g + (size_t)l * 512, n1b + (size_t)l * 512, x, xb, S);
      gemm_bt<2><<<dim3(16, M / 128), 256, 0, stream>>>(xb, wb_f1 + (size_t)l * 2048 * 512,
                                                        f1b + (size_t)l * 2048, big, M, 2048, 512);
      gemm_bt<0><<<dim3(4, M / 128), 256, 0, stream>>>(big, wb_f2 + (size_t)l * 512 * 2048,
                                                       f2b + (size_t)l * 512, tmp, M, 512, 2048);
      ln_k<1><<<M, 128, 0, stream>>>(x, tmp, n2g + (size_t)l * 512, n2b + (size_t)l * 512, x, xb, S);
    }
  };

  // ---- doc encoder, chunked over batches ----
  for (int c0 = 0; c0 < 128; c0 += cb) {
    enc(de + (size_t)c0 * 512 * 512, dmk + (size_t)c0 * 512, 512, cb);
    norm_k<<<cb * 512, 128, 0, stream>>>(x, dn_b + (size_t)c0 * 512 * 512);
  }
  // ---- query encoder (single chunk: 128*32 = 4096 rows <= rows_max) ----
  enc(qe, qm, 32, 128);
  norm_k<<<4096, 128, 0, stream>>>(x, qn_b);

  cos_k<<<dim3(4, 128), 256, 0, stream>>>(qn_b, dn_b, cosb);
  pool_k<<<128, 256, 0, stream>>>(cosb, qm, dmk, pb, pba, dw, out);
}

// Round 4
// 2880.205 us; speedup vs baseline: 1.0012x; 1.0012x over previous
//
#include <hip/hip_runtime.h>
#include <stdint.h>

// ---------------- common ----------------
typedef __bf16 bf16x8 __attribute__((ext_vector_type(8)));
typedef float f32x4 __attribute__((ext_vector_type(4)));
typedef unsigned short u16;
typedef unsigned int u32;

__device__ __forceinline__ u16 f2bf(float f) {
  u32 u = __float_as_uint(f);
  return (u16)((u + 0x7fffu + ((u >> 16) & 1u)) >> 16);
}

__device__ __forceinline__ void gload16(const void* g, void* l) {
  __builtin_amdgcn_global_load_lds((const __attribute__((address_space(1))) u32*)g,
                                   (__attribute__((address_space(3))) u32*)l, 16, 0, 0);
}

__device__ __forceinline__ f32x4 mfma16(bf16x8 a, bf16x8 b, f32x4 c) {
  return __builtin_amdgcn_mfma_f32_16x16x32_bf16(a, b, c, 0, 0, 0);
}

// ---------------- fp32 -> bf16 convert (weights) ----------------
__global__ void cvt_k(const float* __restrict__ in, u16* __restrict__ out, int n4) {
  int i = blockIdx.x * blockDim.x + threadIdx.x;
  int stride = gridDim.x * blockDim.x;
  for (; i < n4; i += stride) {
    float4 v = ((const float4*)in)[i];
    ushort4 o;
    o.x = f2bf(v.x); o.y = f2bf(v.y); o.z = f2bf(v.z); o.w = f2bf(v.w);
    ((ushort4*)out)[i] = o;
  }
}

// ---------------- LayerNorm (row=512). MODE 0: a+pos[row%S]; MODE 1: a+bs[row] ----------------
template<int MODE>
__global__ __launch_bounds__(128) void ln_k(const float* __restrict__ a, const float* __restrict__ bs,
                                            const float* __restrict__ g, const float* __restrict__ be,
                                            float* __restrict__ ox, u16* __restrict__ oxb, int S) {
  int row = blockIdx.x;
  int t = threadIdx.x;
  const float4* ar = (const float4*)(a + (size_t)row * 512);
  size_t brow = (MODE == 0) ? (size_t)(row % S) : (size_t)row;
  const float4* br = (const float4*)(bs + brow * 512);
  float4 va = ar[t], vb = br[t];
  float4 v;
  v.x = va.x + vb.x; v.y = va.y + vb.y; v.z = va.z + vb.z; v.w = va.w + vb.w;
  float s = v.x + v.y + v.z + v.w;
  float sq = v.x * v.x + v.y * v.y + v.z * v.z + v.w * v.w;
#pragma unroll
  for (int m = 1; m < 64; m <<= 1) { s += __shfl_xor(s, m); sq += __shfl_xor(sq, m); }
  __shared__ float red[2][2];
  int wv = t >> 6;
  if ((t & 63) == 0) { red[wv][0] = s; red[wv][1] = sq; }
  __syncthreads();
  s = red[0][0] + red[1][0];
  sq = red[0][1] + red[1][1];
  float mean = s * (1.f / 512.f);
  float var = sq * (1.f / 512.f) - mean * mean;
  float rstd = rsqrtf(var + 1e-5f);
  float4 vg = ((const float4*)g)[t], vbe = ((const float4*)be)[t];
  float4 y;
  y.x = (v.x - mean) * rstd * vg.x + vbe.x;
  y.y = (v.y - mean) * rstd * vg.y + vbe.y;
  y.z = (v.z - mean) * rstd * vg.z + vbe.z;
  y.w = (v.w - mean) * rstd * vg.w + vbe.w;
  ((float4*)(ox + (size_t)row * 512))[t] = y;
  ushort4 yb;
  yb.x = f2bf(y.x); yb.y = f2bf(y.y); yb.z = f2bf(y.z); yb.w = f2bf(y.w);
  ((ushort4*)(oxb + (size_t)row * 512))[t] = yb;
}

// ---------------- row normalize to unit length, write bf16 ----------------
__global__ __launch_bounds__(128) void norm_k(const float* __restrict__ x, u16* __restrict__ o) {
  int row = blockIdx.x;
  int t = threadIdx.x;
  float4 v = ((const float4*)(x + (size_t)row * 512))[t];
  float sq = v.x * v.x + v.y * v.y + v.z * v.z + v.w * v.w;
#pragma unroll
  for (int m = 1; m < 64; m <<= 1) sq += __shfl_xor(sq, m);
  __shared__ float red[2];
  int wv = t >> 6;
  if ((t & 63) == 0) red[wv] = sq;
  __syncthreads();
  sq = red[0] + red[1];
  float rn = 1.f / (sqrtf(sq) + 1e-13f);
  ushort4 yb;
  yb.x = f2bf(v.x * rn); yb.y = f2bf(v.y * rn); yb.z = f2bf(v.z * rn); yb.w = f2bf(v.w * rn);
  ((ushort4*)(o + (size_t)row * 512))[t] = yb;
}

// ---------------- GEMM: C[M,N] = A[M,K] * Bw[N,K]^T + bias. m97-structure, 128x128 tile, BK=64 ----
// OM: 0 -> f32 out, 1 -> bf16 out, 2 -> bf16 relu out
template<int OM>
__global__ __launch_bounds__(256) void gemm_bt(const u16* __restrict__ A, const u16* __restrict__ Bw,
                                               const float* __restrict__ bias, void* __restrict__ Cp,
                                               int M, int N, int Kd) {
  __shared__ __align__(16) u16 As[128 * 64];
  __shared__ __align__(16) u16 Bs[128 * 64];
  const int tid = threadIdx.x;
  const int w = tid >> 6, lane = tid & 63, lr = lane & 15, lg = lane >> 4;
  const int m0 = blockIdx.y * 128, n0 = blockIdx.x * 128;
  const int wr = w >> 1, wc = w & 1;
  f32x4 acc[4][4] = {};
  for (int k0 = 0; k0 < Kd; k0 += 64) {
    __syncthreads();  // previous tile fully consumed
#pragma unroll
    for (int i = 0; i < 4; ++i) {
      int c = tid + 256 * i;
      int r = c >> 3, p = c & 7;
      int lc = p ^ (r & 7);  // pre-swizzled source so linear LDS dest == swizzled layout
      gload16(A + (size_t)(m0 + r) * Kd + k0 + lc * 8, &As[c * 8]);
    }
#pragma unroll
    for (int i = 0; i < 4; ++i) {
      int c = tid + 256 * i;
      int r = c >> 3, p = c & 7;
      int lc = p ^ (r & 7);
      gload16(Bw + (size_t)(n0 + r) * Kd + k0 + lc * 8, &Bs[c * 8]);
    }
    __syncthreads();  // compiler drains vmcnt before barrier
#pragma unroll
    for (int ks = 0; ks < 2; ++ks) {
      bf16x8 af[4], bfr[4];
#pragma unroll
      for (int mi = 0; mi < 4; ++mi) {
        int m = wr * 64 + mi * 16 + lr;
        int ph = (ks * 4 + lg) ^ (m & 7);
        af[mi] = *(const bf16x8*)&As[m * 64 + ph * 8];
      }
#pragma unroll
      for (int ni = 0; ni < 4; ++ni) {
        int n = wc * 64 + ni * 16 + lr;
        int ph = (ks * 4 + lg) ^ (n & 7);
        bfr[ni] = *(const bf16x8*)&Bs[n * 64 + ph * 8];
      }
#pragma unroll
      for (int mi = 0; mi < 4; ++mi)
#pragma unroll
        for (int ni = 0; ni < 4; ++ni)
          acc[mi][ni] = mfma16(af[mi], bfr[ni], acc[mi][ni]);
    }
  }
#pragma unroll
  for (int ni = 0; ni < 4; ++ni) {
    int gn = n0 + wc * 64 + ni * 16 + lr;
    float bv = bias[gn];
#pragma unroll
    for (int mi = 0; mi < 4; ++mi) {
      int gmb = m0 + wr * 64 + mi * 16 + lg * 4;
#pragma unroll
      for (int r = 0; r < 4; ++r) {
        float v = acc[mi][ni][r] + bv;
        size_t off = (size_t)(gmb + r) * N + gn;
        if (OM == 0) {
          ((float*)Cp)[off] = v;
        } else {
          if (OM == 2) v = fmaxf(v, 0.f);
          ((u16*)Cp)[off] = f2bf(v);
        }
      }
    }
  }
}

// ---------------- fused flash attention: block = (b, h, 256 q rows), 4 waves x 4 ti ----------------
// Vt element (d,k) at row d, pos ((k>>3) ^ ((d>>3)&7))*8 + (k&7)  [two-sided XOR swizzle, G4]
__global__ __launch_bounds__(256) void attn_k(const u16* __restrict__ qkv, const float* __restrict__ mask,
                                              u16* __restrict__ ctx, int S, int nQ) {
  __shared__ __align__(16) u16 Kl[128 * 64];
  __shared__ __align__(16) u16 Vt[64 * 136];
  __shared__ __align__(16) u16 Pl[4][16 * 72];
  __shared__ float mb[128];
  const int tid = threadIdx.x, w = tid >> 6, lane = tid & 63, lr = lane & 15, lg = lane >> 4;
  const int bid = blockIdx.x;
  const int b = bid / (8 * nQ);
  const int rem = bid % (8 * nQ);
  const int h = rem / nQ, qb = rem % nQ;
  const int q0 = qb * 256;
  const size_t bbase = (size_t)b * S * 1536;

  bf16x8 aq[4][2];
  bool tv[4];
#pragma unroll
  for (int ti = 0; ti < 4; ++ti) {
    int row = q0 + w * 64 + ti * 16;
    tv[ti] = (row < S);
    if (tv[ti]) {
#pragma unroll
      for (int ks = 0; ks < 2; ++ks)
        aq[ti][ks] = *(const bf16x8*)(qkv + bbase + (size_t)(row + lr) * 1536 + h * 64 + ks * 32 + lg * 8);
    }
  }
  f32x4 o[4][4] = {};
  float mst[4][4], lst[4][4];
#pragma unroll
  for (int ti = 0; ti < 4; ++ti)
#pragma unroll
    for (int r = 0; r < 4; ++r) { mst[ti][r] = -1e30f; lst[ti][r] = 0.f; }

  const int nsc = (S + 127) / 128;
  for (int sc = 0; sc < nsc; ++sc) {
    int base = sc * 128;
    int vs = S - base; if (vs > 128) vs = 128;
    __syncthreads();
    // stage K (swizzled), zero-fill invalid rows
#pragma unroll
    for (int i = 0; i < 4; ++i) {
      int c = tid + 256 * i;
      int rr = c >> 3, p = c & 7;
      int lc = p ^ (rr & 7);
      bf16x8 val = {};
      if (rr < vs) val = *(const bf16x8*)(qkv + bbase + (size_t)(base + rr) * 1536 + 512 + h * 64 + lc * 8);
      *(bf16x8*)&Kl[rr * 64 + p * 8] = val;
    }
    // stage V transposed [64 d rows][128 k cols], XOR-swizzled in 8-col groups
#pragma unroll
    for (int i = 0; i < 4; ++i) {
      int c = tid + 256 * i;
      int rr = c >> 3, p = c & 7;   // rr = k row, p = d octet
      bf16x8 val = {};
      if (rr < vs) val = *(const bf16x8*)(qkv + bbase + (size_t)(base + rr) * 1536 + 1024 + h * 64 + p * 8);
      int pos = (((rr >> 3) ^ p) << 3) + (rr & 7);  // swizzled column slot
#pragma unroll
      for (int j = 0; j < 8; ++j) Vt[(p * 8 + j) * 136 + pos] = ((const u16*)&val)[j];
    }
    if (tid < 128)
      mb[tid] = (tid < vs && mask[(size_t)b * S + base + tid] > 0.f) ? 0.f : -1e9f;
    __syncthreads();

    int nsub = (vs + 63) / 64;
#pragma unroll
    for (int ti = 0; ti < 4; ++ti) {
      if (!tv[ti]) continue;
      for (int sub = 0; sub < nsub; ++sub) {
        f32x4 sf[4] = {};
#pragma unroll
        for (int ks = 0; ks < 2; ++ks) {
#pragma unroll
          for (int ci = 0; ci < 4; ++ci) {
            int rr = sub * 64 + ci * 16 + lr;
            int ph = (ks * 4 + lg) ^ (rr & 7);
            bf16x8 kb = *(const bf16x8*)&Kl[rr * 64 + ph * 8];
            sf[ci] = mfma16(aq[ti][ks], kb, sf[ci]);
          }
        }
        float pv[4][4];
        float cm[4] = {-1e30f, -1e30f, -1e30f, -1e30f};
#pragma unroll
        for (int ci = 0; ci < 4; ++ci) {
          float bia = mb[sub * 64 + ci * 16 + lr];
#pragma unroll
          for (int r = 0; r < 4; ++r) {
            float v = sf[ci][r] * 0.125f + bia;
            pv[ci][r] = v;
            cm[r] = fmaxf(cm[r], v);
          }
        }
#pragma unroll
        for (int r = 0; r < 4; ++r) {
          float v = cm[r];
          v = fmaxf(v, __shfl_xor(v, 1));
          v = fmaxf(v, __shfl_xor(v, 2));
          v = fmaxf(v, __shfl_xor(v, 4));
          v = fmaxf(v, __shfl_xor(v, 8));
          cm[r] = v;
        }
        float al[4];
#pragma unroll
        for (int r = 0; r < 4; ++r) {
          float mn = fmaxf(mst[ti][r], cm[r]);
          al[r] = __expf(mst[ti][r] - mn);
          mst[ti][r] = mn;
        }
        float rs[4] = {0.f, 0.f, 0.f, 0.f};
#pragma unroll
        for (int ci = 0; ci < 4; ++ci)
#pragma unroll
          for (int r = 0; r < 4; ++r) {
            float p = __expf(pv[ci][r] - mst[ti][r]);
            pv[ci][r] = p;
            rs[r] += p;
          }
#pragma unroll
        for (int r = 0; r < 4; ++r) {
          float v = rs[r];
          v += __shfl_xor(v, 1); v += __shfl_xor(v, 2);
          v += __shfl_xor(v, 4); v += __shfl_xor(v, 8);
          lst[ti][r] = lst[ti][r] * al[r] + v;
        }
#pragma unroll
        for (int di = 0; di < 4; ++di)
#pragma unroll
          for (int r = 0; r < 4; ++r) o[ti][di][r] *= al[r];
        // P -> LDS (wave-private), then PV
#pragma unroll
        for (int ci = 0; ci < 4; ++ci)
#pragma unroll
          for (int r = 0; r < 4; ++r)
            Pl[w][(lg * 4 + r) * 72 + ci * 16 + lr] = f2bf(pv[ci][r]);
#pragma unroll
        for (int ks = 0; ks < 2; ++ks) {
          bf16x8 pa = *(const bf16x8*)&Pl[w][lr * 72 + ks * 32 + lg * 8];
#pragma unroll
          for (int di = 0; di < 4; ++di) {
            int vrow = di * 16 + lr;
            int g0 = sub * 8 + ks * 4 + lg;                     // k-col octet
            int pos = ((g0 ^ ((vrow >> 3) & 7)) << 3);          // swizzled, 16B-aligned
            bf16x8 vb = *(const bf16x8*)&Vt[vrow * 136 + pos];
            o[ti][di] = mfma16(pa, vb, o[ti][di]);
          }
        }
      }
    }
  }
  // finalize
#pragma unroll
  for (int ti = 0; ti < 4; ++ti) {
    if (!tv[ti]) continue;
    int rowb = q0 + w * 64 + ti * 16 + lg * 4;
#pragma unroll
    for (int r = 0; r < 4; ++r) {
      float inv = 1.f / lst[ti][r];
#pragma unroll
      for (int di = 0; di < 4; ++di)
        ctx[(size_t)(b * S + rowb + r) * 512 + h * 64 + di * 16 + lr] = f2bf(o[ti][di][r] * inv);
    }
  }
}

// ---------------- batched cosine GEMM: cos[b, 32, 512] = qn[b] * dn[b]^T ----------------
__global__ __launch_bounds__(256) void cos_k(const u16* __restrict__ qn, const u16* __restrict__ dn,
                                             float* __restrict__ cosb) {
  int b = blockIdx.y;
  int n0 = blockIdx.x * 128;
  int tid = threadIdx.x, w = tid >> 6, lane = tid & 63, lr = lane & 15, lg = lane >> 4;
  const u16* qb_ = qn + (size_t)b * 32 * 512;
  const u16* db_ = dn + (size_t)b * 512 * 512;
  f32x4 acc[2][2] = {};
  for (int k0 = 0; k0 < 512; k0 += 32) {
    bf16x8 af[2], bfr[2];
#pragma unroll
    for (int mi = 0; mi < 2; ++mi)
      af[mi] = *(const bf16x8*)(qb_ + (size_t)(mi * 16 + lr) * 512 + k0 + lg * 8);
#pragma unroll
    for (int ni = 0; ni < 2; ++ni)
      bfr[ni] = *(const bf16x8*)(db_ + (size_t)(n0 + w * 32 + ni * 16 + lr) * 512 + k0 + lg * 8);
#pragma unroll
    for (int mi = 0; mi < 2; ++mi)
#pragma unroll
      for (int ni = 0; ni < 2; ++ni) acc[mi][ni] = mfma16(af[mi], bfr[ni], acc[mi][ni]);
  }
#pragma unroll
  for (int mi = 0; mi < 2; ++mi)
#pragma unroll
    for (int ni = 0; ni < 2; ++ni)
#pragma unroll
      for (int r = 0; r < 4; ++r)
        cosb[((size_t)b * 32 + mi * 16 + lg * 4 + r) * 512 + n0 + w * 32 + ni * 16 + lr] = acc[mi][ni][r];
}

// ---------------- kernel pooling + position bias + final dense ----------------
__global__ __launch_bounds__(256) void pool_k(const float* __restrict__ cosb, const float* __restrict__ qm,
                                              const float* __restrict__ dm, const float* __restrict__ pb,
                                              const float* __restrict__ pba, const float* __restrict__ dw,
                                              float* __restrict__ out) {
  const float MUa[11] = {1.0f, 0.9f, 0.7f, 0.5f, 0.3f, 0.1f, -0.1f, -0.3f, -0.5f, -0.7f, -0.9f};
  const float INVa[11] = {500000.f, 50.f, 50.f, 50.f, 50.f, 50.f, 50.f, 50.f, 50.f, 50.f, 50.f};
  int b = blockIdx.x, tid = threadIdx.x, lane = tid & 63, wv = tid >> 6;
  __shared__ float wd[512];
  __shared__ float red[4][11];
  __shared__ float sred[4];
  // doc_len
  float s = dm[(size_t)b * 512 + tid] + dm[(size_t)b * 512 + 256 + tid];
#pragma unroll
  for (int m = 1; m < 64; m <<= 1) s += __shfl_xor(s, m);
  if (lane == 0) sred[wv] = s;
  __syncthreads();
  float L = sred[0] + sred[1] + sred[2] + sred[3];
  int step = (int)rintf(L * 0.1f);
  for (int d = tid; d < 512; d += 256) {
    float mv = dm[(size_t)b * 512 + d];
    int cs = 1;
    if (step > 0) { cs = d / step + 1; if (cs > 10) cs = 10; }
    int pidx = (mv > 0.f) ? cs : 0;
    int aidx = (mv > 0.f) ? (1 + (d >> 6)) : 0;
    wd[d] = ((mv > 0.f) ? 1.f : 0.f) * pb[pidx] * pba[aidx];
  }
  float pk = 0.f;  // valid in tid < 11
  __syncthreads();
  for (int q = 0; q < 32; ++q) {
    float a[11] = {0.f, 0.f, 0.f, 0.f, 0.f, 0.f, 0.f, 0.f, 0.f, 0.f, 0.f};
    for (int d = tid; d < 512; d += 256) {
      float wdv = wd[d];
      if (wdv != 0.f) {
        float c = cosb[((size_t)b * 32 + q) * 512 + d];
#pragma unroll
        for (int k = 0; k < 11; ++k) {
          float t = c - MUa[k];
          a[k] += __expf(-t * t * INVa[k]) * wdv;
        }
      }
    }
#pragma unroll
    for (int k = 0; k < 11; ++k) {
      float v = a[k];
#pragma unroll
      for (int m = 1; m < 64; m <<= 1) v += __shfl_xor(v, m);
      a[k] = v;
    }
    if (lane == 0) {
#pragma unroll
      for (int k = 0; k < 11; ++k) red[wv][k] = a[k];
    }
    __syncthreads();
    if (tid < 11) {
      float sv = red[0][tid] + red[1][tid] + red[2][tid] + red[3][tid];
      pk += qm[(size_t)b * 32 + q] * logf(fmaxf(sv, 1e-10f));
    }
    __syncthreads();
  }
  if (tid < 11) red[0][tid] = pk * dw[tid];
  __syncthreads();
  if (tid == 0) {
    float t = 0.f;
#pragma unroll
    for (int k = 0; k < 11; ++k) t += red[0][k];
    out[b] = t;
  }
}

// ---------------- launch ----------------
extern "C" void kernel_launch(void* const* d_in, const int* in_sizes, int n_in,
                              void* d_out, int out_size, void* d_ws, size_t ws_size,
                              hipStream_t stream) {
  (void)in_sizes; (void)n_in; (void)out_size;
  const float* qe  = (const float*)d_in[0];
  const float* de  = (const float*)d_in[1];
  const float* qm  = (const float*)d_in[2];
  const float* dmk = (const float*)d_in[3];
  const float* pos = (const float*)d_in[4];
  const float* lng = (const float*)d_in[5];
  const float* lnb = (const float*)d_in[6];
  const float* iw  = (const float*)d_in[7];
  const float* ib  = (const float*)d_in[8];
  const float* ow  = (const float*)d_in[9];
  const float* ob  = (const float*)d_in[10];
  const float* f1w = (const float*)d_in[11];
  const float* f1b = (const float*)d_in[12];
  const float* f2w = (const float*)d_in[13];
  const float* f2b = (const float*)d_in[14];
  const float* n1g = (const float*)d_in[15];
  const float* n1b = (const float*)d_in[16];
  const float* n2g = (const float*)d_in[17];
  const float* n2b = (const float*)d_in[18];
  const float* dw  = (const float*)d_in[19];
  const float* pb  = (const float*)d_in[20];
  const float* pba = (const float*)d_in[21];
  float* out = (float*)d_out;

  uint8_t* ws = (uint8_t*)d_ws;
  size_t off = 0;
  auto alloc = [&](size_t bytes) -> void* {
    void* p = ws + off;
    off += (bytes + 255) & ~(size_t)255;
    return p;
  };
  auto a256 = [](size_t b) -> size_t { return (b + 255) & ~(size_t)255; };

  // ---- persistent buffers ----
  u16* wb_iw = (u16*)alloc((size_t)2 * 1536 * 512 * 2);
  u16* wb_ow = (u16*)alloc((size_t)2 * 512 * 512 * 2);
  u16* wb_f1 = (u16*)alloc((size_t)2 * 2048 * 512 * 2);
  u16* wb_f2 = (u16*)alloc((size_t)2 * 512 * 2048 * 2);
  u16* qn_b  = (u16*)alloc((size_t)4096 * 512 * 2);     // normalized query, bf16
  u16* dn_b  = (u16*)alloc((size_t)65536 * 512 * 2);    // normalized doc, bf16
  float* cosb = (float*)alloc((size_t)128 * 32 * 512 * 4);

  // ---- adaptive chunk size: cb docs per chunk (rows = cb*512) ----
  // chunk scratch = rows*(x:2048 + xb:1024 + big:4096 + tmp:2048) bytes = rows*9216
  int cb = 128;
  while (cb > 8) {
    size_t rows = (size_t)cb * 512;
    size_t chunk = a256(rows * 512 * 4) + a256(rows * 512 * 2) +
                   a256(rows * 2048 * 2) + a256(rows * 512 * 4);
    if (off + chunk <= ws_size) break;
    cb >>= 1;
  }
  size_t rows_max = (size_t)cb * 512;  // >= 4096 (query chunk) since cb >= 8
  float* x   = (float*)alloc(rows_max * 512 * 4);
  u16* xb    = (u16*)alloc(rows_max * 512 * 2);
  u16* big   = (u16*)alloc(rows_max * 2048 * 2);  // qkv [rows,1536] + ctx [rows,512] tail; later ff-hidden [rows,2048]
  float* tmp = (float*)alloc(rows_max * 512 * 4);

  // weights -> bf16 (same work every call; graph-safe)
  cvt_k<<<1024, 256, 0, stream>>>(iw,  wb_iw, 2 * 1536 * 512 / 4);
  cvt_k<<<1024, 256, 0, stream>>>(ow,  wb_ow, 2 * 512 * 512 / 4);
  cvt_k<<<1024, 256, 0, stream>>>(f1w, wb_f1, 2 * 2048 * 512 / 4);
  cvt_k<<<1024, 256, 0, stream>>>(f2w, wb_f2, 2 * 512 * 2048 / 4);

  // one encoder pass over `nb` batch rows of length S (M = nb*S rows resident in chunk scratch)
  auto enc = [&](const float* emb, const float* mask, int S, int nb) {
    int M = nb * S;
    u16* ctxb = big + (size_t)M * 1536;  // packed after qkv
    ln_k<0><<<M, 128, 0, stream>>>(emb, pos, lng, lnb, x, xb, S);
    int nQ = (S + 255) / 256;
    for (int l = 0; l < 2; ++l) {
      gemm_bt<1><<<dim3(12, M / 128), 256, 0, stream>>>(xb, wb_iw + (size_t)l * 1536 * 512,
                                                        ib + (size_t)l * 1536, big, M, 1536, 512);
      attn_k<<<nb * 8 * nQ, 256, 0, stream>>>(big, mask, ctxb, S, nQ);
      gemm_bt<0><<<dim3(4, M / 128), 256, 0, stream>>>(ctxb, wb_ow + (size_t)l * 512 * 512,
                                                       ob + (size_t)l * 512, tmp, M, 512, 512);
      ln_k<1><<<M, 128, 0, stream>>>(x, tmp, n1g + (size_t)l * 512, n1b + (size_t)l * 512, x, xb, S);
      gemm_bt<2><<<dim3(16, M / 128), 256, 0, stream>>>(xb, wb_f1 + (size_t)l * 2048 * 512,
                                                        f1b + (size_t)l * 2048, big, M, 2048, 512);
      gemm_bt<0><<<dim3(4, M / 128), 256, 0, stream>>>(big, wb_f2 + (size_t)l * 512 * 2048,
                                                       f2b + (size_t)l * 512, tmp, M, 512, 2048);
      ln_k<1><<<M, 128, 0, stream>>>(x, tmp, n2g + (size_t)l * 512, n2b + (size_t)l * 512, x, xb, S);
    }
  };

  // ---- doc encoder, chunked over batches ----
  for (int c0 = 0; c0 < 128; c0 += cb) {
    enc(de + (size_t)c0 * 512 * 512, dmk + (size_t)c0 * 512, 512, cb);
    norm_k<<<cb * 512, 128, 0, stream>>>(x, dn_b + (size_t)c0 * 512 * 512);
  }
  // ---- query encoder (single chunk: 128*32 = 4096 rows <= rows_max) ----
  enc(qe, qm, 32, 128);
  norm_k<<<4096, 128, 0, stream>>>(x, qn_b);

  cos_k<<<dim3(4, 128), 256, 0, stream>>>(qn_b, dn_b, cosb);
  pool_k<<<128, 256, 0, stream>>>(cosb, qm, dmk, pb, pba, dw, out);
}